// Round 7
// baseline (314.468 us; speedup 1.0000x reference)
//
#include <hip/hip_runtime.h>

// DynamicSparseMultiHeadAttention on MI355X (gfx950).
// B=4, L=2048, D_MODEL=512, H=8, D_K=D_V=64, TEMP=8, WINDOW=2, THRESH=0.5.
// d_out = [ out (4*2048*512 f32) | attn (32*2048*2048 f32) ].
// ~50% of rows are gate-closed (window-only): compacted split —
//   role A: full flash attention on gathered open rows (MFMA),
//   role B: zero-fill + 5-wide window softmax for closed rows (streaming).

typedef _Float16 f16;
typedef _Float16 f16x8 __attribute__((ext_vector_type(8)));
typedef _Float16 f16x4 __attribute__((ext_vector_type(4)));
typedef float f32x4 __attribute__((ext_vector_type(4)));

#define OUT0_ELEMS (4 * 2048 * 512)

__device__ __forceinline__ f16x8 cvt8(float4 a, float4 b) {
  f16x8 r;
  r[0] = (f16)a.x; r[1] = (f16)a.y; r[2] = (f16)a.z; r[3] = (f16)a.w;
  r[4] = (f16)b.x; r[5] = (f16)b.y; r[6] = (f16)b.z; r[7] = (f16)b.w;
  return r;
}

// ---------------- K0: prep (f64 effective gate weight) ----------------
__global__ __launch_bounds__(256) void prep_kernel(
    const float* __restrict__ w_q, const float* __restrict__ b_q,
    const float* __restrict__ w_g, const float* __restrict__ b_g,
    double* __restrict__ wge, double* __restrict__ bqg) {
  int idx = blockIdx.x * 256 + threadIdx.x;
  if (idx < 4096) {
    int h = idx >> 9, c = idx & 511;
    double acc = 0.0;
    for (int d = 0; d < 64; ++d)
      acc += (double)w_g[d] * (double)w_q[(h * 64 + d) * 512 + c];
    wge[idx] = acc;
  }
  if (idx < 8) {
    double acc = (double)b_g[0];
    for (int d = 0; d < 64; ++d)
      acc += (double)b_q[idx * 64 + d] * (double)w_g[d];
    bqg[idx] = acc;
  }
}

// ---------------- K1: gate logits (f64, one wave per token) ----------------
__global__ __launch_bounds__(256) void gate_kernel(
    const float* __restrict__ q, const double* __restrict__ wge,
    const double* __restrict__ bqg, int* __restrict__ gate) {
  int lane = threadIdx.x & 63, wid = threadIdx.x >> 6;
  int tok = blockIdx.x * 4 + wid;  // 0..8191 = b*2048 + l
  int b = tok >> 11, l = tok & 2047;
  const float* qr = q + (long)tok * 512;
  float qv[8];
#pragma unroll
  for (int j = 0; j < 8; ++j) qv[j] = qr[lane + 64 * j];
#pragma unroll
  for (int h = 0; h < 8; ++h) {
    double acc = 0.0;
#pragma unroll
    for (int j = 0; j < 8; ++j) acc += (double)qv[j] * wge[h * 512 + lane + 64 * j];
#pragma unroll
    for (int off = 1; off < 64; off <<= 1) acc += __shfl_xor(acc, off);
    double logit = acc + bqg[h];
    if (lane == 0) gate[(h * 4 + b) * 2048 + l] = (logit > 0.0) ? 1 : 0;
  }
}

// ---------------- K1b: stable partition rows into open|closed ----------------
__global__ __launch_bounds__(256) void compact_kernel(
    const int* __restrict__ gate, unsigned short* __restrict__ perm,
    int* __restrict__ nopen) {
  __shared__ int wsum[4];
  const int hb = blockIdx.x, t = threadIdx.x;
  const int lane = t & 63, wid = t >> 6;
  const int base = hb * 2048;
  int g[8];
  int cnt = 0;
#pragma unroll
  for (int i = 0; i < 8; ++i) { g[i] = gate[base + t * 8 + i]; cnt += g[i]; }
  int inc = cnt;
#pragma unroll
  for (int off = 1; off < 64; off <<= 1) {
    int y = __shfl_up(inc, off);
    if (lane >= off) inc += y;
  }
  if (lane == 63) wsum[wid] = inc;
  __syncthreads();
  int wbase = 0;
  for (int w = 0; w < wid; ++w) wbase += wsum[w];
  const int totOpen = wsum[0] + wsum[1] + wsum[2] + wsum[3];
  int openPos = wbase + inc - cnt;                 // exclusive open prefix
  int closedPos = totOpen + t * 8 - openPos;       // closed region offset
#pragma unroll
  for (int i = 0; i < 8; ++i) {
    int l = t * 8 + i;
    if (g[i]) perm[base + openPos++] = (unsigned short)l;
    else      perm[base + closedPos++] = (unsigned short)l;
  }
  if (t == 0) nopen[hb] = totOpen;
}

// ---------------- K2/K4a: f16 MFMA GEMM, M=8192, N=K=512 ----------------
template <int EPI>
__global__ __launch_bounds__(256) void gemm512(
    const float* __restrict__ A, const float* __restrict__ W,
    const float* __restrict__ bias, const float* __restrict__ res,
    f16* __restrict__ out16, float* __restrict__ outf) {
  __shared__ __align__(16) f16 As[64 * 32];
  __shared__ __align__(16) f16 Ws[64 * 32];
  const int tid = threadIdx.x;
  const int lane = tid & 63, wid = tid >> 6;
  const int lo = lane & 15, hi = lane >> 4;
  const int m0 = blockIdx.x * 64, n0 = blockIdx.y * 64;
  const int wm = wid >> 1, wn = wid & 1;

  const int srow = tid >> 2, sseg = tid & 3;
  const int ssu = sseg ^ (srow & 3);
  const float* gA = A + (long)(m0 + srow) * 512 + sseg * 8;
  const float* gW = W + (long)(n0 + srow) * 512 + sseg * 8;
  f16* wA = &As[srow * 32 + ssu * 8];
  f16* wW = &Ws[srow * 32 + ssu * 8];

  const f32x4 zero4 = {0.f, 0.f, 0.f, 0.f};
  f32x4 acc[2][2] = {{zero4, zero4}, {zero4, zero4}};
  const int ra0 = wm * 32 + lo;
  const int rb0 = wn * 32 + lo;
  const int sa = hi ^ (ra0 & 3);
  const int sb = hi ^ (rb0 & 3);

  for (int kk = 0; kk < 512; kk += 32) {
    float4 a0 = *(const float4*)(gA + kk);
    float4 a1 = *(const float4*)(gA + kk + 4);
    float4 w0 = *(const float4*)(gW + kk);
    float4 w1 = *(const float4*)(gW + kk + 4);
    *(f16x8*)wA = cvt8(a0, a1);
    *(f16x8*)wW = cvt8(w0, w1);
    __syncthreads();
    f16x8 af0 = *(const f16x8*)&As[ra0 * 32 + sa * 8];
    f16x8 af1 = *(const f16x8*)&As[(ra0 + 16) * 32 + sa * 8];
    f16x8 bf0 = *(const f16x8*)&Ws[rb0 * 32 + sb * 8];
    f16x8 bf1 = *(const f16x8*)&Ws[(rb0 + 16) * 32 + sb * 8];
    acc[0][0] = __builtin_amdgcn_mfma_f32_16x16x32_f16(af0, bf0, acc[0][0], 0, 0, 0);
    acc[0][1] = __builtin_amdgcn_mfma_f32_16x16x32_f16(af0, bf1, acc[0][1], 0, 0, 0);
    acc[1][0] = __builtin_amdgcn_mfma_f32_16x16x32_f16(af1, bf0, acc[1][0], 0, 0, 0);
    acc[1][1] = __builtin_amdgcn_mfma_f32_16x16x32_f16(af1, bf1, acc[1][1], 0, 0, 0);
    __syncthreads();
  }

#pragma unroll
  for (int i = 0; i < 2; ++i)
#pragma unroll
    for (int j = 0; j < 2; ++j)
#pragma unroll
      for (int r = 0; r < 4; ++r) {
        const int m = m0 + wm * 32 + i * 16 + hi * 4 + r;
        const int n = n0 + wn * 32 + j * 16 + lo;
        float v = acc[i][j][r] + bias[n];
        if constexpr (EPI == 0) {
          const int b = m >> 11, l = m & 2047, h = n >> 6, d = n & 63;
          out16[(long)((h * 4 + b) * 2048 + l) * 64 + d] = (f16)v;
        } else if constexpr (EPI == 2) {
          const int b = m >> 11, l = m & 2047, h = n >> 6, d = n & 63;
          out16[(long)((h * 4 + b) * 64 + d) * 2048 + l] = (f16)v;
        } else {
          outf[(long)m * 512 + n] = v + res[(long)m * 512 + n];
        }
      }
}

// ---------- staging: 64x64 f16 tile, linear global, XOR-swizzled LDS -------
struct Stg2 { uint4 d0, d1; };

__device__ __forceinline__ Stg2 ldK(const f16* __restrict__ g, int tid) {
  Stg2 s;
  s.d0 = *(const uint4*)(g + tid * 8);
  s.d1 = *(const uint4*)(g + 2048 + tid * 8);
  return s;
}

__device__ __forceinline__ Stg2 ldV(const f16* __restrict__ g, int tid) {
  const int row = tid >> 3, seg = tid & 7;
  const f16* p = g + (long)row * 2048 + seg * 8;
  Stg2 s;
  s.d0 = *(const uint4*)p;
  s.d1 = *(const uint4*)(p + 32 * 2048);
  return s;
}

__device__ __forceinline__ void stW(const Stg2& s, f16* lds, int tid) {
  const int row = tid >> 3, seg = tid & 7, sw = row & 7;
  *(uint4*)&lds[(row << 6) + ((seg ^ sw) << 3)] = s.d0;
  *(uint4*)&lds[((row + 32) << 6) + ((seg ^ sw) << 3)] = s.d1;
}

// ---------------- K3: fused attention (role A: open rows, role B: closed) --
__global__ __launch_bounds__(256) void attn_kernel(
    const f16* __restrict__ qh, const f16* __restrict__ kh,
    const f16* __restrict__ vt, const int* __restrict__ gate,
    const unsigned short* __restrict__ perm, const int* __restrict__ nopen,
    float* __restrict__ attn, float* __restrict__ o) {
  __shared__ __align__(16) f16 Ks[2][4096];
  __shared__ __align__(16) f16 Vs[2][4096];
  __shared__ __align__(16) f16 Ps[4][1024];
  const int tid = threadIdx.x;
  const int lane = tid & 63, wid = tid >> 6;
  const int bid = blockIdx.x;

  if (bid >= 1024) {
    // ---------------- role B: closed rows (window-only) ----------------
    const int vb = bid - 1024;
    const int hb = vb >> 5, chunk = vb & 31;
    const int nop = nopen[hb];
    const int j0 = ((nop + 63) & ~63) + (chunk << 6);
    if (j0 >= 2048) return;
    unsigned short* rowIdx = (unsigned short*)&Ks[0][0];
    if (tid < 64) rowIdx[tid] = perm[hb * 2048 + j0 + tid];
    __syncthreads();
    // phase 1: zero-fill 64 rows x 2048 f32 (coalesced f32x4)
    float* abase = attn + ((long)hb * 2048 << 11);
    const f32x4 zero4 = {0.f, 0.f, 0.f, 0.f};
#pragma unroll 4
    for (int it = 0; it < 128; ++it) {
      const int c = tid + (it << 8);
      const int ri = c >> 9;
      const int col = (c & 511) << 2;
      *(f32x4*)(abase + ((long)rowIdx[ri] << 11) + col) = zero4;
    }
    __syncthreads();
    // phase 2: window softmax + PV for 16 rows per wave
    const f16* qhb = qh + (long)hb * 2048 * 64;
    const f16* khb = kh + (long)hb * 2048 * 64;
    const f16* vtb = vt + (long)hb * 64 * 2048;
    const int b = hb & 3, h = hb >> 2;
    for (int rr = 0; rr < 16; ++rr) {
      const int row = rowIdx[(wid << 4) + rr];
      const int jlo = max(row - 2, 0), jhi = min(row + 2, 2047);
      const float qv = (float)qhb[(long)row * 64 + lane];
      float p0, p1, p2, p3, p4, sum = 0.f;
#pragma unroll
      for (int jj = 0; jj < 5; ++jj) {
        const int j = jlo + jj;
        const int js = min(j, 2047);
        float prod = qv * (float)khb[(long)js * 64 + lane];
        prod += __shfl_xor(prod, 1);
        prod += __shfl_xor(prod, 2);
        prod += __shfl_xor(prod, 4);
        prod += __shfl_xor(prod, 8);
        prod += __shfl_xor(prod, 16);
        prod += __shfl_xor(prod, 32);
        const float e = (j <= jhi) ? __expf(prod * 0.125f) : 0.f;
        if (jj == 0) p0 = e; else if (jj == 1) p1 = e; else if (jj == 2) p2 = e;
        else if (jj == 3) p3 = e; else p4 = e;
        sum += e;
      }
      const float inv = 1.f / sum;
      // patch window values (lanes 0..4)
      float pv = p0;
      pv = (lane == 1) ? p1 : pv;
      pv = (lane == 2) ? p2 : pv;
      pv = (lane == 3) ? p3 : pv;
      pv = (lane == 4) ? p4 : pv;
      if (lane < 5 && (jlo + lane) <= jhi)
        abase[((long)row << 11) + jlo + lane] = pv * inv;
      // PV: lane = d
      float od = 0.f;
      od += p0 * (float)vtb[(long)lane * 2048 + min(jlo + 0, 2047)];
      od += p1 * (float)vtb[(long)lane * 2048 + min(jlo + 1, 2047)];
      od += p2 * (float)vtb[(long)lane * 2048 + min(jlo + 2, 2047)];
      od += p3 * (float)vtb[(long)lane * 2048 + min(jlo + 3, 2047)];
      od += p4 * (float)vtb[(long)lane * 2048 + min(jlo + 4, 2047)];
      o[(long)(b * 2048 + row) * 512 + (h << 6) + lane] = od * inv;
    }
    return;
  }

  // ---------------- role A: open rows, full flash attention ----------------
  const int lo = lane & 15, hi = lane >> 4;
  // XCD-aware swizzle: 1024 A-blocks = 8 XCDs x 128; XCD x owns hb [4x,4x+4)
  const int xcd = bid & 7, local = bid >> 3;
  const int hb = xcd * 4 + (local >> 5);
  const int q0 = (local & 31) << 6;
  const int nop = nopen[hb];
  if (q0 >= nop) return;  // rows beyond ceil64(nop) handled by role B

  const unsigned short* pm = perm + hb * 2048 + q0;
  const f16* khb = kh + (long)hb * 2048 * 64;
  const f16* vtb = vt + (long)hb * 64 * 2048;

  // Q A-fragment, gathered rows
  const int rowA = pm[(wid << 4) + lo];
  const f16* qrow = qh + (long)(hb * 2048 + rowA) * 64;
  const f16x8 aq0 = *(const f16x8*)(qrow + (hi << 3));
  const f16x8 aq1 = *(const f16x8*)(qrow + 32 + (hi << 3));

  int qi[4], gt[4];
  float psum[4];
#pragma unroll
  for (int r = 0; r < 4; ++r) {
    qi[r] = pm[(wid << 4) + (hi << 2) + r];
    gt[r] = gate[hb * 2048 + qi[r]];
    psum[r] = 0.f;
  }
  const f32x4 zero4 = {0.f, 0.f, 0.f, 0.f};

  // ---- pass 1: row sums of exp(S/8) ----
  {
    Stg2 kreg = ldK(khb, tid);
    stW(kreg, &Ks[0][0], tid);
    kreg = ldK(khb + 4096, tid);
    int cur = 0;
    for (int kt = 0; kt < 32; ++kt) {
      __syncthreads();
      if (kt < 31) {
        stW(kreg, &Ks[cur ^ 1][0], tid);
        if (kt < 30) kreg = ldK(khb + (long)(kt + 2) * 4096, tid);
      }
      const f16* Kc = &Ks[cur][0];
      f32x4 sacc[4] = {zero4, zero4, zero4, zero4};
      __builtin_amdgcn_s_setprio(1);
#pragma unroll
      for (int s = 0; s < 2; ++s) {
        const f16x8 a = s ? aq1 : aq0;
#pragma unroll
        for (int nt = 0; nt < 4; ++nt) {
          const int krow = (nt << 4) + lo;
          const f16x8 b = *(const f16x8*)&Kc[(krow << 6) + ((((s << 2) + hi) ^ (krow & 7)) << 3)];
          sacc[nt] = __builtin_amdgcn_mfma_f32_16x16x32_f16(a, b, sacc[nt], 0, 0, 0);
        }
      }
      __builtin_amdgcn_s_setprio(0);
      const int kkb = (kt << 6) + lo;
#pragma unroll
      for (int nt = 0; nt < 4; ++nt) {
        const int kk = kkb + (nt << 4);
#pragma unroll
        for (int r = 0; r < 4; ++r) {
          const bool allowed = gt[r] || ((unsigned)(kk - qi[r] + 2) <= 4u);
          psum[r] += allowed ? __expf(sacc[nt][r] * 0.125f) : 0.f;
        }
      }
      cur ^= 1;
    }
  }

  float invl[4];
#pragma unroll
  for (int r = 0; r < 4; ++r) {
    float s = psum[r];
    s += __shfl_xor(s, 1);
    s += __shfl_xor(s, 2);
    s += __shfl_xor(s, 4);
    s += __shfl_xor(s, 8);
    invl[r] = 1.f / s;
  }

  // ---- pass 2: recompute S, write normalized p, PV ----
  f32x4 oacc[4] = {zero4, zero4, zero4, zero4};
  f16* Pw = &Ps[wid][0];
  const int row2 = lane >> 2, qq = lane & 3;
  float* arow = attn + ((long)(hb * 2048 + pm[(wid << 4) + row2]) << 11);

  {
    Stg2 kreg = ldK(khb, tid);
    Stg2 vreg = ldV(vtb, tid);
    stW(kreg, &Ks[0][0], tid);
    stW(vreg, &Vs[0][0], tid);
    kreg = ldK(khb + 4096, tid);
    vreg = ldV(vtb + 64, tid);
    int cur = 0;
    for (int kt = 0; kt < 32; ++kt) {
      __syncthreads();
      if (kt < 31) {
        stW(kreg, &Ks[cur ^ 1][0], tid);
        stW(vreg, &Vs[cur ^ 1][0], tid);
        if (kt < 30) {
          kreg = ldK(khb + (long)(kt + 2) * 4096, tid);
          vreg = ldV(vtb + ((kt + 2) << 6), tid);
        }
      }
      const f16* Kc = &Ks[cur][0];
      const f16* Vc = &Vs[cur][0];
      f32x4 sacc[4] = {zero4, zero4, zero4, zero4};
      __builtin_amdgcn_s_setprio(1);
#pragma unroll
      for (int s = 0; s < 2; ++s) {
        const f16x8 a = s ? aq1 : aq0;
#pragma unroll
        for (int nt = 0; nt < 4; ++nt) {
          const int krow = (nt << 4) + lo;
          const f16x8 b = *(const f16x8*)&Kc[(krow << 6) + ((((s << 2) + hi) ^ (krow & 7)) << 3)];
          sacc[nt] = __builtin_amdgcn_mfma_f32_16x16x32_f16(a, b, sacc[nt], 0, 0, 0);
        }
      }
      __builtin_amdgcn_s_setprio(0);
      const int kkb = (kt << 6) + lo;
#pragma unroll
      for (int nt = 0; nt < 4; ++nt) {
        const int kk = kkb + (nt << 4);
#pragma unroll
        for (int r = 0; r < 4; ++r) {
          const bool allowed = gt[r] || ((unsigned)(kk - qi[r] + 2) <= 4u);
          const float p = allowed ? __expf(sacc[nt][r] * 0.125f) * invl[r] : 0.f;
          const int prow = (hi << 2) + r;
          const int pcol = (nt << 4) + lo;
          Pw[(prow << 6) + (((pcol >> 3) ^ (prow & 7)) << 3) + (pcol & 7)] = (f16)p;
        }
      }
      __builtin_amdgcn_s_setprio(1);
#pragma unroll
      for (int s = 0; s < 2; ++s) {
        const f16x8 ap = *(const f16x8*)&Pw[(lo << 6) + ((((s << 2) + hi) ^ (lo & 7)) << 3)];
#pragma unroll
        for (int nt = 0; nt < 4; ++nt) {
          const int vrow = (nt << 4) + lo;
          const f16x8 bv = *(const f16x8*)&Vc[(vrow << 6) + ((((s << 2) + hi) ^ (vrow & 7)) << 3)];
          oacc[nt] = __builtin_amdgcn_mfma_f32_16x16x32_f16(ap, bv, oacc[nt], 0, 0, 0);
        }
      }
      __builtin_amdgcn_s_setprio(0);
      {
        const int swz = row2 & 7;
        float* dst = arow + (kt << 6) + (qq << 2);
#pragma unroll
        for (int i = 0; i < 4; ++i) {
          const f16x4 pv = *(const f16x4*)&Pw[(row2 << 6) + ((((i << 1) + (qq >> 1)) ^ swz) << 3) + ((qq & 1) << 2)];
          f32x4 fo = {(float)pv[0], (float)pv[1], (float)pv[2], (float)pv[3]};
          *(f32x4*)(dst + (i << 4)) = fo;
        }
      }
      cur ^= 1;
    }
  }

  const int b = hb & 3, h = hb >> 2;
#pragma unroll
  for (int nt = 0; nt < 4; ++nt)
#pragma unroll
    for (int r = 0; r < 4; ++r)
      o[(long)(b * 2048 + qi[r]) * 512 + (h << 6) + (nt << 4) + lo] = oacc[nt][r];
}

// ---------------- K4b: LayerNorm in place on d_out[0:out0] ----------------
__global__ __launch_bounds__(256) void ln_kernel(float* __restrict__ x,
                                                 const float* __restrict__ g,
                                                 const float* __restrict__ bta) {
  __shared__ float red[8];
  const int t = threadIdx.x;
  float* row = x + (long)blockIdx.x * 512;
  float v0 = row[t], v1 = row[t + 256];
  float s = v0 + v1;
#pragma unroll
  for (int off = 1; off < 64; off <<= 1) s += __shfl_xor(s, off);
  if ((t & 63) == 0) red[t >> 6] = s;
  __syncthreads();
  const float mean = (red[0] + red[1] + red[2] + red[3]) * (1.f / 512.f);
  const float d0 = v0 - mean, d1 = v1 - mean;
  float sq = d0 * d0 + d1 * d1;
#pragma unroll
  for (int off = 1; off < 64; off <<= 1) sq += __shfl_xor(sq, off);
  if ((t & 63) == 0) red[4 + (t >> 6)] = sq;
  __syncthreads();
  const float var = (red[4] + red[5] + red[6] + red[7]) * (1.f / 512.f);
  const float rstd = 1.f / sqrtf(var + 1e-5f);
  row[t] = d0 * rstd * g[t] + bta[t];
  row[t + 256] = d1 * rstd * g[t + 256] + bta[t + 256];
}

extern "C" void kernel_launch(void* const* d_in, const int* in_sizes, int n_in,
                              void* d_out, int out_size, void* d_ws, size_t ws_size,
                              hipStream_t stream) {
  const float* q    = (const float*)d_in[0];
  const float* k    = (const float*)d_in[1];
  const float* v    = (const float*)d_in[2];
  const float* w_q  = (const float*)d_in[3];
  const float* b_q  = (const float*)d_in[4];
  const float* w_k  = (const float*)d_in[5];
  const float* b_k  = (const float*)d_in[6];
  const float* w_v  = (const float*)d_in[7];
  const float* b_v  = (const float*)d_in[8];
  const float* w_g  = (const float*)d_in[9];
  const float* b_g  = (const float*)d_in[10];
  const float* w_fc = (const float*)d_in[11];
  const float* b_fc = (const float*)d_in[12];
  const float* ln_g = (const float*)d_in[13];
  const float* ln_b = (const float*)d_in[14];

  char* wsb = (char*)d_ws;
  f16* qh16   = (f16*)wsb;                       // 8,388,608 B
  f16* kh16   = qh16 + 4194304;                  // 8,388,608 B
  f16* vt16   = kh16 + 4194304;                  // 8,388,608 B
  float* ob   = (float*)(wsb + 25165824);        // 16,777,216 B
  int* gateb  = (int*)(wsb + 25165824 + 16777216);              // 262,144 B
  double* wge = (double*)(wsb + 25165824 + 16777216 + 262144);  // 32,768 B
  double* bqg = wge + 4096;                      // 64 B
  unsigned short* permb = (unsigned short*)(wsb + 25165824 + 16777216 + 262144 + 32768 + 64);  // 131,072 B
  int* nopenb = (int*)(wsb + 25165824 + 16777216 + 262144 + 32768 + 64 + 131072);              // 128 B

  float* out0 = (float*)d_out;
  float* attn = out0 + OUT0_ELEMS;

  prep_kernel<<<16, 256, 0, stream>>>(w_q, b_q, w_g, b_g, wge, bqg);
  gate_kernel<<<2048, 256, 0, stream>>>(q, wge, bqg, gateb);
  compact_kernel<<<32, 256, 0, stream>>>(gateb, permb, nopenb);

  dim3 gp(128, 8);
  gemm512<0><<<gp, 256, 0, stream>>>(q, w_q, b_q, nullptr, qh16, nullptr);
  gemm512<0><<<gp, 256, 0, stream>>>(k, w_k, b_k, nullptr, kh16, nullptr);
  gemm512<2><<<gp, 256, 0, stream>>>(v, w_v, b_v, nullptr, vt16, nullptr);

  attn_kernel<<<2048, 256, 0, stream>>>(qh16, kh16, vt16, gateb, permb, nopenb, attn, ob);

  gemm512<3><<<gp, 256, 0, stream>>>(ob, w_fc, b_fc, q, nullptr, out0);
  ln_kernel<<<8192, 256, 0, stream>>>(out0, ln_g, ln_b);
}

// Round 8
// 269.618 us; speedup vs baseline: 1.1663x; 1.1663x over previous
//
#include <hip/hip_runtime.h>

// DynamicSparseMultiHeadAttention on MI355X (gfx950).
// B=4, L=2048, D_MODEL=512, H=8, D_K=D_V=64, TEMP=8, WINDOW=2, THRESH=0.5.
// d_out = [ out (4*2048*512 f32) | attn (32*2048*2048 f32) ].
// Compacted split: role A = flash attention on open rows (8 waves, 128 rows,
// LDS-only barriers so stores/prefetch stay in flight); role B = zero-fill +
// 5-wide window softmax for closed rows (XCD-coherent mapping).

typedef _Float16 f16;
typedef _Float16 f16x8 __attribute__((ext_vector_type(8)));
typedef _Float16 f16x4 __attribute__((ext_vector_type(4)));
typedef float f32x4 __attribute__((ext_vector_type(4)));

#define OUT0_ELEMS (4 * 2048 * 512)

__device__ __forceinline__ f16x8 cvt8(float4 a, float4 b) {
  f16x8 r;
  r[0] = (f16)a.x; r[1] = (f16)a.y; r[2] = (f16)a.z; r[3] = (f16)a.w;
  r[4] = (f16)b.x; r[5] = (f16)b.y; r[6] = (f16)b.z; r[7] = (f16)b.w;
  return r;
}

// barrier that waits only LDS ops (wave-local lgkmcnt covers own ds_read/
// ds_write); global stores/loads stay in flight across the barrier.
__device__ __forceinline__ void bar_lds() {
  asm volatile("s_waitcnt lgkmcnt(0)" ::: "memory");
  __builtin_amdgcn_s_barrier();
}

// ---------------- K0: prep (f64 effective gate weight) ----------------
__global__ __launch_bounds__(256) void prep_kernel(
    const float* __restrict__ w_q, const float* __restrict__ b_q,
    const float* __restrict__ w_g, const float* __restrict__ b_g,
    double* __restrict__ wge, double* __restrict__ bqg) {
  int idx = blockIdx.x * 256 + threadIdx.x;
  if (idx < 4096) {
    int h = idx >> 9, c = idx & 511;
    double acc = 0.0;
    for (int d = 0; d < 64; ++d)
      acc += (double)w_g[d] * (double)w_q[(h * 64 + d) * 512 + c];
    wge[idx] = acc;
  }
  if (idx < 8) {
    double acc = (double)b_g[0];
    for (int d = 0; d < 64; ++d)
      acc += (double)b_q[idx * 64 + d] * (double)w_g[d];
    bqg[idx] = acc;
  }
}

// ---------------- K1: gate logits (f64, one wave per token) ----------------
__global__ __launch_bounds__(256) void gate_kernel(
    const float* __restrict__ q, const double* __restrict__ wge,
    const double* __restrict__ bqg, int* __restrict__ gate) {
  int lane = threadIdx.x & 63, wid = threadIdx.x >> 6;
  int tok = blockIdx.x * 4 + wid;  // 0..8191 = b*2048 + l
  int b = tok >> 11, l = tok & 2047;
  const float* qr = q + (long)tok * 512;
  float qv[8];
#pragma unroll
  for (int j = 0; j < 8; ++j) qv[j] = qr[lane + 64 * j];
#pragma unroll
  for (int h = 0; h < 8; ++h) {
    double acc = 0.0;
#pragma unroll
    for (int j = 0; j < 8; ++j) acc += (double)qv[j] * wge[h * 512 + lane + 64 * j];
#pragma unroll
    for (int off = 1; off < 64; off <<= 1) acc += __shfl_xor(acc, off);
    double logit = acc + bqg[h];
    if (lane == 0) gate[(h * 4 + b) * 2048 + l] = (logit > 0.0) ? 1 : 0;
  }
}

// ---------------- K1b: stable partition rows into open|closed --------------
__global__ __launch_bounds__(256) void compact_kernel(
    const int* __restrict__ gate, unsigned short* __restrict__ perm,
    int* __restrict__ nopen) {
  __shared__ int wsum[4];
  const int hb = blockIdx.x, t = threadIdx.x;
  const int lane = t & 63, wid = t >> 6;
  const int base = hb * 2048;
  int g[8];
  int cnt = 0;
#pragma unroll
  for (int i = 0; i < 8; ++i) { g[i] = gate[base + t * 8 + i]; cnt += g[i]; }
  int inc = cnt;
#pragma unroll
  for (int off = 1; off < 64; off <<= 1) {
    int y = __shfl_up(inc, off);
    if (lane >= off) inc += y;
  }
  if (lane == 63) wsum[wid] = inc;
  __syncthreads();
  int wbase = 0;
  for (int w = 0; w < wid; ++w) wbase += wsum[w];
  const int totOpen = wsum[0] + wsum[1] + wsum[2] + wsum[3];
  int openPos = wbase + inc - cnt;                 // exclusive open prefix
  int closedPos = totOpen + t * 8 - openPos;       // closed region offset
#pragma unroll
  for (int i = 0; i < 8; ++i) {
    int l = t * 8 + i;
    if (g[i]) perm[base + openPos++] = (unsigned short)l;
    else      perm[base + closedPos++] = (unsigned short)l;
  }
  if (t == 0) nopen[hb] = totOpen;
}

// ---------------- K2/K4a: f16 MFMA GEMM, M=8192, N=K=512 ----------------
template <int EPI>
__global__ __launch_bounds__(256) void gemm512(
    const float* __restrict__ A, const float* __restrict__ W,
    const float* __restrict__ bias, const float* __restrict__ res,
    f16* __restrict__ out16, float* __restrict__ outf) {
  __shared__ __align__(16) f16 As[64 * 32];
  __shared__ __align__(16) f16 Ws[64 * 32];
  const int tid = threadIdx.x;
  const int lane = tid & 63, wid = tid >> 6;
  const int lo = lane & 15, hi = lane >> 4;
  const int m0 = blockIdx.x * 64, n0 = blockIdx.y * 64;
  const int wm = wid >> 1, wn = wid & 1;

  const int srow = tid >> 2, sseg = tid & 3;
  const int ssu = sseg ^ (srow & 3);
  const float* gA = A + (long)(m0 + srow) * 512 + sseg * 8;
  const float* gW = W + (long)(n0 + srow) * 512 + sseg * 8;
  f16* wA = &As[srow * 32 + ssu * 8];
  f16* wW = &Ws[srow * 32 + ssu * 8];

  const f32x4 zero4 = {0.f, 0.f, 0.f, 0.f};
  f32x4 acc[2][2] = {{zero4, zero4}, {zero4, zero4}};
  const int ra0 = wm * 32 + lo;
  const int rb0 = wn * 32 + lo;
  const int sa = hi ^ (ra0 & 3);
  const int sb = hi ^ (rb0 & 3);

  for (int kk = 0; kk < 512; kk += 32) {
    float4 a0 = *(const float4*)(gA + kk);
    float4 a1 = *(const float4*)(gA + kk + 4);
    float4 w0 = *(const float4*)(gW + kk);
    float4 w1 = *(const float4*)(gW + kk + 4);
    *(f16x8*)wA = cvt8(a0, a1);
    *(f16x8*)wW = cvt8(w0, w1);
    __syncthreads();
    f16x8 af0 = *(const f16x8*)&As[ra0 * 32 + sa * 8];
    f16x8 af1 = *(const f16x8*)&As[(ra0 + 16) * 32 + sa * 8];
    f16x8 bf0 = *(const f16x8*)&Ws[rb0 * 32 + sb * 8];
    f16x8 bf1 = *(const f16x8*)&Ws[(rb0 + 16) * 32 + sb * 8];
    acc[0][0] = __builtin_amdgcn_mfma_f32_16x16x32_f16(af0, bf0, acc[0][0], 0, 0, 0);
    acc[0][1] = __builtin_amdgcn_mfma_f32_16x16x32_f16(af0, bf1, acc[0][1], 0, 0, 0);
    acc[1][0] = __builtin_amdgcn_mfma_f32_16x16x32_f16(af1, bf0, acc[1][0], 0, 0, 0);
    acc[1][1] = __builtin_amdgcn_mfma_f32_16x16x32_f16(af1, bf1, acc[1][1], 0, 0, 0);
    __syncthreads();
  }

#pragma unroll
  for (int i = 0; i < 2; ++i)
#pragma unroll
    for (int j = 0; j < 2; ++j)
#pragma unroll
      for (int r = 0; r < 4; ++r) {
        const int m = m0 + wm * 32 + i * 16 + hi * 4 + r;
        const int n = n0 + wn * 32 + j * 16 + lo;
        float v = acc[i][j][r] + bias[n];
        if constexpr (EPI == 0) {
          const int b = m >> 11, l = m & 2047, h = n >> 6, d = n & 63;
          out16[(long)((h * 4 + b) * 2048 + l) * 64 + d] = (f16)v;
        } else if constexpr (EPI == 2) {
          const int b = m >> 11, l = m & 2047, h = n >> 6, d = n & 63;
          out16[(long)((h * 4 + b) * 64 + d) * 2048 + l] = (f16)v;
        } else {
          outf[(long)m * 512 + n] = v + res[(long)m * 512 + n];
        }
      }
}

// ---------- 512-thread staging: 64x64 f16 tile, XOR-swizzled LDS ----------
__device__ __forceinline__ uint4 ldK512(const f16* __restrict__ g, int tid) {
  return *(const uint4*)(g + tid * 8);                       // 8 KB contiguous
}
__device__ __forceinline__ uint4 ldV512(const f16* __restrict__ g, int tid) {
  return *(const uint4*)(g + (long)(tid >> 3) * 2048 + ((tid & 7) << 3));
}
__device__ __forceinline__ void stW512(uint4 s, f16* lds, int tid) {
  const int row = tid >> 3, seg = tid & 7, sw = row & 7;
  *(uint4*)&lds[(row << 6) + ((seg ^ sw) << 3)] = s;
}

// ---------------- K3: fused attention (A: open rows, B: closed) -----------
__global__ __launch_bounds__(512) void attn_kernel(
    const f16* __restrict__ qh, const f16* __restrict__ kh,
    const f16* __restrict__ vt, const int* __restrict__ gate,
    const unsigned short* __restrict__ perm, const int* __restrict__ nopen,
    float* __restrict__ attn, float* __restrict__ o) {
  __shared__ __align__(16) f16 Ks[2][4096];
  __shared__ __align__(16) f16 Vs[2][4096];
  __shared__ __align__(16) f16 Ps[8][1024];
  const int tid = threadIdx.x;
  const int lane = tid & 63, wid = tid >> 6;   // wid 0..7
  const int bid = blockIdx.x;

  if (bid >= 512) {
    // ---------------- role B: closed rows (window-only) ----------------
    const int vb = bid - 512;                  // 0..1023
    const int xcd = vb & 7, sub = vb >> 3;     // XCD-coherent hb mapping
    const int hb = xcd * 4 + (sub >> 5);
    const int chunk = sub & 31;
    const int nop = nopen[hb];
    const int j0 = ((nop + 127) & ~127) + (chunk << 6);
    if (j0 >= 2048) return;
    unsigned short* rowIdx = (unsigned short*)&Ks[0][0];
    if (tid < 64) rowIdx[tid] = perm[hb * 2048 + j0 + tid];
    __syncthreads();
    // phase 1: zero-fill 64 rows x 8 KB; one full row per instruction
    float* abase = attn + ((long)hb * 2048 << 11);
    const f32x4 zero4 = {0.f, 0.f, 0.f, 0.f};
    for (int it = 0; it < 64; ++it)
      *(f32x4*)(abase + ((long)rowIdx[it] << 11) + (tid << 2)) = zero4;
    __syncthreads();
    // phase 2: window softmax + PV, 8 rows per wave
    const f16* qhb = qh + (long)hb * 2048 * 64;
    const f16* khb = kh + (long)hb * 2048 * 64;
    const f16* vtb = vt + (long)hb * 64 * 2048;
    const int b = hb & 3, h = hb >> 2;
    for (int rr = 0; rr < 8; ++rr) {
      const int row = rowIdx[(wid << 3) + rr];
      const int jlo = max(row - 2, 0), jhi = min(row + 2, 2047);
      const float qv = (float)qhb[(long)row * 64 + lane];
      float p0, p1, p2, p3, p4, sum = 0.f;
#pragma unroll
      for (int jj = 0; jj < 5; ++jj) {
        const int j = jlo + jj;
        const int js = min(j, 2047);
        float prod = qv * (float)khb[(long)js * 64 + lane];
        prod += __shfl_xor(prod, 1);
        prod += __shfl_xor(prod, 2);
        prod += __shfl_xor(prod, 4);
        prod += __shfl_xor(prod, 8);
        prod += __shfl_xor(prod, 16);
        prod += __shfl_xor(prod, 32);
        const float e = (j <= jhi) ? __expf(prod * 0.125f) : 0.f;
        if (jj == 0) p0 = e; else if (jj == 1) p1 = e; else if (jj == 2) p2 = e;
        else if (jj == 3) p3 = e; else p4 = e;
        sum += e;
      }
      const float inv = 1.f / sum;
      float pv = p0;
      pv = (lane == 1) ? p1 : pv;
      pv = (lane == 2) ? p2 : pv;
      pv = (lane == 3) ? p3 : pv;
      pv = (lane == 4) ? p4 : pv;
      if (lane < 5 && (jlo + lane) <= jhi)
        abase[((long)row << 11) + jlo + lane] = pv * inv;
      float od = 0.f;
      od += p0 * (float)vtb[(long)lane * 2048 + min(jlo + 0, 2047)];
      od += p1 * (float)vtb[(long)lane * 2048 + min(jlo + 1, 2047)];
      od += p2 * (float)vtb[(long)lane * 2048 + min(jlo + 2, 2047)];
      od += p3 * (float)vtb[(long)lane * 2048 + min(jlo + 3, 2047)];
      od += p4 * (float)vtb[(long)lane * 2048 + min(jlo + 4, 2047)];
      o[(long)(b * 2048 + row) * 512 + (h << 6) + lane] = od * inv;
    }
    return;
  }

  // ---------------- role A: open rows, full flash attention ----------------
  const int lo = lane & 15, hi = lane >> 4;
  // 512 A-blocks = 8 XCDs x 64; XCD x owns hb [4x,4x+4); 16 tiles of 128 rows
  const int xcd = bid & 7, local = bid >> 3;
  const int hb = xcd * 4 + (local >> 4);
  const int q0 = (local & 15) << 7;
  const int nop = nopen[hb];
  if (q0 >= nop) return;  // rows beyond ceil128(nop) handled by role B

  const unsigned short* pm = perm + hb * 2048 + q0;
  const f16* khb = kh + (long)hb * 2048 * 64;
  const f16* vtb = vt + (long)hb * 64 * 2048;

  // Q A-fragment, gathered rows
  const int rowA = pm[(wid << 4) + lo];
  const f16* qrow = qh + (long)(hb * 2048 + rowA) * 64;
  const f16x8 aq0 = *(const f16x8*)(qrow + (hi << 3));
  const f16x8 aq1 = *(const f16x8*)(qrow + 32 + (hi << 3));

  int qi[4], gt[4];
  float psum[4];
#pragma unroll
  for (int r = 0; r < 4; ++r) {
    qi[r] = pm[(wid << 4) + (hi << 2) + r];
    gt[r] = gate[hb * 2048 + qi[r]];
    psum[r] = 0.f;
  }
  const f32x4 zero4 = {0.f, 0.f, 0.f, 0.f};

  // ---- pass 1: row sums of exp(S/8) ----
  {
    uint4 kreg = ldK512(khb, tid);
    stW512(kreg, &Ks[0][0], tid);
    kreg = ldK512(khb + 4096, tid);
    int cur = 0;
    for (int kt = 0; kt < 32; ++kt) {
      bar_lds();
      if (kt < 31) {
        stW512(kreg, &Ks[cur ^ 1][0], tid);
        if (kt < 30) kreg = ldK512(khb + (long)(kt + 2) * 4096, tid);
      }
      const f16* Kc = &Ks[cur][0];
      f32x4 sacc[4] = {zero4, zero4, zero4, zero4};
      __builtin_amdgcn_s_setprio(1);
#pragma unroll
      for (int s = 0; s < 2; ++s) {
        const f16x8 a = s ? aq1 : aq0;
#pragma unroll
        for (int nt = 0; nt < 4; ++nt) {
          const int krow = (nt << 4) + lo;
          const f16x8 b = *(const f16x8*)&Kc[(krow << 6) + ((((s << 2) + hi) ^ (krow & 7)) << 3)];
          sacc[nt] = __builtin_amdgcn_mfma_f32_16x16x32_f16(a, b, sacc[nt], 0, 0, 0);
        }
      }
      __builtin_amdgcn_s_setprio(0);
      const int kkb = (kt << 6) + lo;
#pragma unroll
      for (int nt = 0; nt < 4; ++nt) {
        const int kk = kkb + (nt << 4);
#pragma unroll
        for (int r = 0; r < 4; ++r) {
          const bool allowed = gt[r] || ((unsigned)(kk - qi[r] + 2) <= 4u);
          psum[r] += allowed ? __expf(sacc[nt][r] * 0.125f) : 0.f;
        }
      }
      cur ^= 1;
    }
  }

  float invl[4];
#pragma unroll
  for (int r = 0; r < 4; ++r) {
    float s = psum[r];
    s += __shfl_xor(s, 1);
    s += __shfl_xor(s, 2);
    s += __shfl_xor(s, 4);
    s += __shfl_xor(s, 8);
    invl[r] = 1.f / s;
  }

  // ---- pass 2: recompute S, write normalized p, PV ----
  f32x4 oacc[4] = {zero4, zero4, zero4, zero4};
  f16* Pw = &Ps[wid][0];
  const int row2 = lane >> 2, qq = lane & 3;
  float* arow = attn + ((long)(hb * 2048 + pm[(wid << 4) + row2]) << 11);

  {
    uint4 kreg = ldK512(khb, tid);
    uint4 vreg = ldV512(vtb, tid);
    stW512(kreg, &Ks[0][0], tid);
    stW512(vreg, &Vs[0][0], tid);
    kreg = ldK512(khb + 4096, tid);
    vreg = ldV512(vtb + 64, tid);
    int cur = 0;
    for (int kt = 0; kt < 32; ++kt) {
      bar_lds();
      if (kt < 31) {
        stW512(kreg, &Ks[cur ^ 1][0], tid);
        stW512(vreg, &Vs[cur ^ 1][0], tid);
        if (kt < 30) {
          kreg = ldK512(khb + (long)(kt + 2) * 4096, tid);
          vreg = ldV512(vtb + ((kt + 2) << 6), tid);
        }
      }
      const f16* Kc = &Ks[cur][0];
      const f16* Vc = &Vs[cur][0];
      f32x4 sacc[4] = {zero4, zero4, zero4, zero4};
      __builtin_amdgcn_s_setprio(1);
#pragma unroll
      for (int s = 0; s < 2; ++s) {
        const f16x8 a = s ? aq1 : aq0;
#pragma unroll
        for (int nt = 0; nt < 4; ++nt) {
          const int krow = (nt << 4) + lo;
          const f16x8 b = *(const f16x8*)&Kc[(krow << 6) + ((((s << 2) + hi) ^ (krow & 7)) << 3)];
          sacc[nt] = __builtin_amdgcn_mfma_f32_16x16x32_f16(a, b, sacc[nt], 0, 0, 0);
        }
      }
      __builtin_amdgcn_s_setprio(0);
      const int kkb = (kt << 6) + lo;
#pragma unroll
      for (int nt = 0; nt < 4; ++nt) {
        const int kk = kkb + (nt << 4);
#pragma unroll
        for (int r = 0; r < 4; ++r) {
          const bool allowed = gt[r] || ((unsigned)(kk - qi[r] + 2) <= 4u);
          const float p = allowed ? __expf(sacc[nt][r] * 0.125f) * invl[r] : 0.f;
          const int prow = (hi << 2) + r;
          const int pcol = (nt << 4) + lo;
          Pw[(prow << 6) + (((pcol >> 3) ^ (prow & 7)) << 3) + (pcol & 7)] = (f16)p;
        }
      }
      __builtin_amdgcn_s_setprio(1);
#pragma unroll
      for (int s = 0; s < 2; ++s) {
        const f16x8 ap = *(const f16x8*)&Pw[(lo << 6) + ((((s << 2) + hi) ^ (lo & 7)) << 3)];
#pragma unroll
        for (int nt = 0; nt < 4; ++nt) {
          const int vrow = (nt << 4) + lo;
          const f16x8 bv = *(const f16x8*)&Vc[(vrow << 6) + ((((s << 2) + hi) ^ (vrow & 7)) << 3)];
          oacc[nt] = __builtin_amdgcn_mfma_f32_16x16x32_f16(ap, bv, oacc[nt], 0, 0, 0);
        }
      }
      __builtin_amdgcn_s_setprio(0);
      {
        const int swz = row2 & 7;
        float* dst = arow + (kt << 6) + (qq << 2);
#pragma unroll
        for (int i = 0; i < 4; ++i) {
          const f16x4 pv = *(const f16x4*)&Pw[(row2 << 6) + ((((i << 1) + (qq >> 1)) ^ swz) << 3) + ((qq & 1) << 2)];
          f32x4 fo = {(float)pv[0], (float)pv[1], (float)pv[2], (float)pv[3]};
          *(f32x4*)(dst + (i << 4)) = fo;
        }
      }
      cur ^= 1;
    }
  }

  const int b = hb & 3, h = hb >> 2;
#pragma unroll
  for (int nt = 0; nt < 4; ++nt)
#pragma unroll
    for (int r = 0; r < 4; ++r)
      o[(long)(b * 2048 + qi[r]) * 512 + (h << 6) + (nt << 4) + lo] = oacc[nt][r];
}

// ---------------- K4b: LayerNorm in place on d_out[0:out0] ----------------
__global__ __launch_bounds__(256) void ln_kernel(float* __restrict__ x,
                                                 const float* __restrict__ g,
                                                 const float* __restrict__ bta) {
  __shared__ float red[8];
  const int t = threadIdx.x;
  float* row = x + (long)blockIdx.x * 512;
  float v0 = row[t], v1 = row[t + 256];
  float s = v0 + v1;
#pragma unroll
  for (int off = 1; off < 64; off <<= 1) s += __shfl_xor(s, off);
  if ((t & 63) == 0) red[t >> 6] = s;
  __syncthreads();
  const float mean = (red[0] + red[1] + red[2] + red[3]) * (1.f / 512.f);
  const float d0 = v0 - mean, d1 = v1 - mean;
  float sq = d0 * d0 + d1 * d1;
#pragma unroll
  for (int off = 1; off < 64; off <<= 1) sq += __shfl_xor(sq, off);
  if ((t & 63) == 0) red[4 + (t >> 6)] = sq;
  __syncthreads();
  const float var = (red[4] + red[5] + red[6] + red[7]) * (1.f / 512.f);
  const float rstd = 1.f / sqrtf(var + 1e-5f);
  row[t] = d0 * rstd * g[t] + bta[t];
  row[t + 256] = d1 * rstd * g[t + 256] + bta[t + 256];
}

extern "C" void kernel_launch(void* const* d_in, const int* in_sizes, int n_in,
                              void* d_out, int out_size, void* d_ws, size_t ws_size,
                              hipStream_t stream) {
  const float* q    = (const float*)d_in[0];
  const float* k    = (const float*)d_in[1];
  const float* v    = (const float*)d_in[2];
  const float* w_q  = (const float*)d_in[3];
  const float* b_q  = (const float*)d_in[4];
  const float* w_k  = (const float*)d_in[5];
  const float* b_k  = (const float*)d_in[6];
  const float* w_v  = (const float*)d_in[7];
  const float* b_v  = (const float*)d_in[8];
  const float* w_g  = (const float*)d_in[9];
  const float* b_g  = (const float*)d_in[10];
  const float* w_fc = (const float*)d_in[11];
  const float* b_fc = (const float*)d_in[12];
  const float* ln_g = (const float*)d_in[13];
  const float* ln_b = (const float*)d_in[14];

  char* wsb = (char*)d_ws;
  f16* qh16   = (f16*)wsb;                       // 8,388,608 B
  f16* kh16   = qh16 + 4194304;                  // 8,388,608 B
  f16* vt16   = kh16 + 4194304;                  // 8,388,608 B
  float* ob   = (float*)(wsb + 25165824);        // 16,777,216 B
  int* gateb  = (int*)(wsb + 25165824 + 16777216);              // 262,144 B
  double* wge = (double*)(wsb + 25165824 + 16777216 + 262144);  // 32,768 B
  double* bqg = wge + 4096;                      // 64 B
  unsigned short* permb = (unsigned short*)(wsb + 25165824 + 16777216 + 262144 + 32768 + 64);  // 131,072 B
  int* nopenb = (int*)(wsb + 25165824 + 16777216 + 262144 + 32768 + 64 + 131072);              // 128 B

  float* out0 = (float*)d_out;
  float* attn = out0 + OUT0_ELEMS;

  prep_kernel<<<16, 256, 0, stream>>>(w_q, b_q, w_g, b_g, wge, bqg);
  gate_kernel<<<2048, 256, 0, stream>>>(q, wge, bqg, gateb);
  compact_kernel<<<32, 256, 0, stream>>>(gateb, permb, nopenb);

  dim3 gp(128, 8);
  gemm512<0><<<gp, 256, 0, stream>>>(q, w_q, b_q, nullptr, qh16, nullptr);
  gemm512<0><<<gp, 256, 0, stream>>>(k, w_k, b_k, nullptr, kh16, nullptr);
  gemm512<2><<<gp, 256, 0, stream>>>(v, w_v, b_v, nullptr, vt16, nullptr);

  attn_kernel<<<1536, 512, 0, stream>>>(qh16, kh16, vt16, gateb, permb, nopenb, attn, ob);

  gemm512<3><<<gp, 256, 0, stream>>>(ob, w_fc, b_fc, q, nullptr, out0);
  ln_kernel<<<8192, 256, 0, stream>>>(out0, ln_g, ln_b);
}